// Round 1
// baseline (667.740 us; speedup 1.0000x reference)
//
#include <hip/hip_runtime.h>

// MeshConv R3: out[e][o] = b[o] + sum_k combined[e][k] * W[o][k], K=160, OUT=64.
// Theory: R2 is service-rate-bound on the L2-miss path (~3.5 TB/s, queues full
// per Little's law). R3 attacks bytes+transactions+overhead:
//  (1) stage x as fp16 in d_ws (separate kernel): gather rows 128B->64B, ONE
//      coalesced 64B transaction per row, random hot set 128MB->64MB (L3-safe
//      under the 250MB nt write stream). fp16 err (5e-4) << bf16 descriptor
//      rounding already present -> absmax unchanged.
//  (2) MFMA operand swap: A/B frags of 16x16x32 are layout-symmetric, so
//      mfma(W_frag, x_frag, acc) yields acc[tn][r] = out[e=col][o=tn*16+quad*4+r]
//      -> direct f32x4 nt stores, t_lds (17KB) + transpose + bank conflicts gone.
//  (3) occupancy probe: LDS 20.7KB, fp16 halves gather buffers ->
//      __launch_bounds__(256,6) targets 24 waves/CU (was 16). nbr prefetched
//      2 tiles ahead so the nbr->gather serial dependency is off-path.
// Fallback: if ws_size < 64MB, run the proven R2 f32 kernel unchanged.

typedef __bf16    bf16_t;
typedef __bf16    bf16x8 __attribute__((ext_vector_type(8)));
typedef _Float16  f16_t;
typedef _Float16  f16x8  __attribute__((ext_vector_type(8)));
typedef float     f32x4  __attribute__((ext_vector_type(4)));

#define EC        1000000
#define CCH       32
#define OUTD      64
#define KD        160          // 5*CCH
#define MT        64           // elements per tile
#define NTILES    (EC / MT)    // 15625
#define NFRAG     1280         // 5 ks * 4 tn * 4 quad * 16 col frags of 8 bf16
#define GRID_F16  1536         // 6 blocks/CU * 256 CUs
#define CVT_GRID  2048
#define TSTR      68           // R2 fallback epilogue stride
#define GRID_F32  1024

// ---------------------------------------------------------------------------
// staging: x f32 -> f16 image in workspace (nt loads: dead f32 stays out of L3)
// ---------------------------------------------------------------------------
__global__ __launch_bounds__(256)
void cvt_x_f16(const float* __restrict__ x, f16_t* __restrict__ xh)
{
    const size_t n8     = (size_t)EC * CCH / 8;     // 4,000,000 groups of 8
    const size_t stride = (size_t)CVT_GRID * 256;
    size_t i = (size_t)blockIdx.x * 256 + threadIdx.x;
    for (; i < n8; i += stride) {
        const f32x4* p = (const f32x4*)x + 2 * i;
        f32x4 a = __builtin_nontemporal_load(p);
        f32x4 b = __builtin_nontemporal_load(p + 1);
        f16x8 h;
        h[0]=(f16_t)a[0]; h[1]=(f16_t)a[1]; h[2]=(f16_t)a[2]; h[3]=(f16_t)a[3];
        h[4]=(f16_t)b[0]; h[5]=(f16_t)b[1]; h[6]=(f16_t)b[2]; h[7]=(f16_t)b[3];
        *((f16x8*)xh + i) = h;                       // cached store: L3-resident
    }
}

// ---------------------------------------------------------------------------
// main fp16-gather kernel
// ---------------------------------------------------------------------------
__global__ __launch_bounds__(256, 6)
void meshconv_f16(const f16_t* __restrict__ xh,
                  const int*   __restrict__ nbr,
                  const float* __restrict__ W,
                  const float* __restrict__ bias,
                  float*       __restrict__ out)
{
    __shared__ bf16_t w_lds[NFRAG * 8];                          // 20.0 KB
    __shared__ __attribute__((aligned(16))) float b_lds[OUTD];   // 256 B

    const int tid  = threadIdx.x;
    const int wave = tid >> 6;
    const int lane = tid & 63;
    const int col  = lane & 15;
    const int quad = lane >> 4;

    // one-time: W (64x160 f32) -> bf16 LDS, frag-swizzled.
    // w_lds frag(ks,tn,quad,col,j) = W[tn*16+col][ks*32+quad*8+j]
    //   == A-operand layout (o = lane&15, k = quad*8+j) for the swapped MFMA.
    for (int i = tid; i < NFRAG; i += 256) {
        const int fc  = i & 15;
        const int fq  = (i >> 4) & 3;
        const int ftn = (i >> 6) & 3;
        const int fks = i >> 8;
        const float* src = W + (ftn * 16 + fc) * KD + fks * 32 + fq * 8;
        f32x4 w0 = *(const f32x4*)src;
        f32x4 w1 = *(const f32x4*)(src + 4);
        bf16x8 wf;
        wf[0]=(bf16_t)w0[0]; wf[1]=(bf16_t)w0[1]; wf[2]=(bf16_t)w0[2]; wf[3]=(bf16_t)w0[3];
        wf[4]=(bf16_t)w1[0]; wf[5]=(bf16_t)w1[1]; wf[6]=(bf16_t)w1[2]; wf[7]=(bf16_t)w1[3];
        *(bf16x8*)&w_lds[i * 8] = wf;
    }
    if (tid < 16) *(f32x4*)&b_lds[tid * 4] = ((const f32x4*)bias)[tid];

    __syncthreads();   // w_lds/b_lds ready; read-only hereafter

    auto ld_nbr = [&](int t) -> int4 {
        return ((const int4*)nbr)[t * MT + wave * 16 + col];
    };
    // 5 rows x 8 channels (this lane's quad slice), 16B = ONE 64B line per row
    auto gather = [&](int t, const int4& nb, f16x8* buf) {
        const int e  = t * MT + wave * 16 + col;
        const int i0 = nb.x < 0 ? 0 : nb.x;
        const int i1 = nb.y < 0 ? 0 : nb.y;
        const int i2 = nb.z < 0 ? 0 : nb.z;
        const int i3 = nb.w < 0 ? 0 : nb.w;
        const int co = quad * 8;
        buf[0] = *(const f16x8*)(xh + (size_t)e  * CCH + co);
        buf[1] = *(const f16x8*)(xh + (size_t)i0 * CCH + co);
        buf[2] = *(const f16x8*)(xh + (size_t)i1 * CCH + co);
        buf[3] = *(const f16x8*)(xh + (size_t)i2 * CCH + co);
        buf[4] = *(const f16x8*)(xh + (size_t)i3 * CCH + co);
    };

    int tile = blockIdx.x;
    int4  nb_cur, nb_nxt;
    f16x8 cb[5];
    if (tile < NTILES) {
        nb_cur = ld_nbr(tile);                  // prologue: serial once
        gather(tile, nb_cur, cb);
        const int t1 = (tile + GRID_F16 < NTILES) ? tile + GRID_F16 : tile;
        nb_nxt = ld_nbr(t1);                    // nbr one tile ahead, in flight
    }

    for (; tile < NTILES; tile += GRID_F16) {
        const int nxt = tile + GRID_F16;
        f16x8 pb[5];
        int4  nb2 = nb_nxt;
        if (nxt < NTILES) {
            gather(nxt, nb_nxt, pb);            // nbr already resident: no stall
            const int t2 = (nxt + GRID_F16 < NTILES) ? nxt + GRID_F16 : nxt;
            nb2 = ld_nbr(t2);                   // nbr two tiles ahead
        }

        // ---- descriptor slices == the 5 B-frags (e = lane&15, k = quad*8+j) ----
        const float m0 = nb_cur.x < 0 ? 0.f : 1.f;
        const float m1 = nb_cur.y < 0 ? 0.f : 1.f;
        const float m2 = nb_cur.z < 0 ? 0.f : 1.f;
        const float m3 = nb_cur.w < 0 ? 0.f : 1.f;

        bf16x8 af[5];
#pragma unroll
        for (int jj = 0; jj < 8; ++jj) {
            const float va0 = (float)cb[1][jj] * m0;
            const float va1 = (float)cb[2][jj] * m1;
            const float vb0 = (float)cb[3][jj] * m2;
            const float vb1 = (float)cb[4][jj] * m3;
            const float sa = va0 + va1;
            const float da = fabsf(va0 - va1);
            const float sb = vb0 + vb1;
            const float db = fabsf(vb0 - vb1);
            af[0][jj] = (bf16_t)(float)cb[0][jj];
            af[1][jj] = (bf16_t)(sa + sb);
            af[2][jj] = (bf16_t)(da + db);
            af[3][jj] = (bf16_t)fabsf(sa - sb);
            af[4][jj] = (bf16_t)fabsf(da - db);
        }

        // ---- swapped MFMA: acc[tn][r] = out[e = col][o = tn*16 + quad*4 + r] ----
        f32x4 acc[4];
#pragma unroll
        for (int tn = 0; tn < 4; ++tn)
            acc[tn] = *(const f32x4*)&b_lds[tn * 16 + quad * 4];  // bias init (broadcast)
#pragma unroll
        for (int ks = 0; ks < 5; ++ks) {
#pragma unroll
            for (int tn = 0; tn < 4; ++tn) {
                const bf16x8 wfr = *(const bf16x8*)&w_lds[(((ks*4+tn)*4+quad)*16 + col) * 8];
                acc[tn] = __builtin_amdgcn_mfma_f32_16x16x32_bf16(wfr, af[ks], acc[tn], 0, 0, 0);
            }
        }

        // ---- direct epilogue: 4 consecutive o-channels per lane, nt 16B stores ----
        {
            float* ob = out + (size_t)(tile * MT + wave * 16 + col) * OUTD + quad * 4;
#pragma unroll
            for (int tn = 0; tn < 4; ++tn)
                __builtin_nontemporal_store(acc[tn], (f32x4*)(ob + tn * 16));
        }

        // ---- rotate pipeline ----
        nb_cur = nb_nxt;
        nb_nxt = nb2;
#pragma unroll
        for (int k = 0; k < 5; ++k) cb[k] = pb[k];
    }
}

// ---------------------------------------------------------------------------
// R2 fallback (proven): f32 gathers + LDS-transpose epilogue. Used only if the
// workspace cannot hold the 64MB fp16 image.
// ---------------------------------------------------------------------------
__global__ __launch_bounds__(256)
void meshconv_kernel(const float* __restrict__ x,
                     const int*   __restrict__ nbr,
                     const float* __restrict__ W,
                     const float* __restrict__ bias,
                     float*       __restrict__ out)
{
    __shared__ bf16_t w_lds[NFRAG * 8];
    __shared__ __attribute__((aligned(16))) float t_lds[4 * 16 * TSTR];

    const int tid  = threadIdx.x;
    const int wave = tid >> 6;
    const int lane = tid & 63;
    const int col  = lane & 15;
    const int quad = lane >> 4;

    for (int i = tid; i < NFRAG; i += 256) {
        const int fc  = i & 15;
        const int fq  = (i >> 4) & 3;
        const int ftn = (i >> 6) & 3;
        const int fks = i >> 8;
        const float* src = W + (ftn * 16 + fc) * KD + fks * 32 + fq * 8;
        f32x4 w0 = *(const f32x4*)src;
        f32x4 w1 = *(const f32x4*)(src + 4);
        bf16x8 wf;
        wf[0]=(bf16_t)w0[0]; wf[1]=(bf16_t)w0[1]; wf[2]=(bf16_t)w0[2]; wf[3]=(bf16_t)w0[3];
        wf[4]=(bf16_t)w1[0]; wf[5]=(bf16_t)w1[1]; wf[6]=(bf16_t)w1[2]; wf[7]=(bf16_t)w1[3];
        *(bf16x8*)&w_lds[i * 8] = wf;
    }

    float bv[4];
#pragma unroll
    for (int tn = 0; tn < 4; ++tn) bv[tn] = bias[tn * 16 + col];

    float* tw = &t_lds[wave * 16 * TSTR];

    __syncthreads();

    auto load_tile = [&](int t, int4& nb, f32x4* buf) {
        const int e = t * MT + wave * 16 + col;
        nb = ((const int4*)nbr)[e];
        const int i0 = nb.x < 0 ? 0 : nb.x;
        const int i1 = nb.y < 0 ? 0 : nb.y;
        const int i2 = nb.z < 0 ? 0 : nb.z;
        const int i3 = nb.w < 0 ? 0 : nb.w;
        const int co = quad * 8;
        const f32x4* p;
        p = (const f32x4*)(x + (size_t)e  * CCH + co); buf[0] = p[0]; buf[1] = p[1];
        p = (const f32x4*)(x + (size_t)i0 * CCH + co); buf[2] = p[0]; buf[3] = p[1];
        p = (const f32x4*)(x + (size_t)i1 * CCH + co); buf[4] = p[0]; buf[5] = p[1];
        p = (const f32x4*)(x + (size_t)i2 * CCH + co); buf[6] = p[0]; buf[7] = p[1];
        p = (const f32x4*)(x + (size_t)i3 * CCH + co); buf[8] = p[0]; buf[9] = p[1];
    };

    int tile = blockIdx.x;
    int4  nbc;
    f32x4 cb[10];
    if (tile < NTILES) load_tile(tile, nbc, cb);

    for (; tile < NTILES; tile += GRID_F32) {
        const int nxt = tile + GRID_F32;
        int4  nbn;
        f32x4 pbuf[10];
        if (nxt < NTILES) load_tile(nxt, nbn, pbuf);

        const float m0 = nbc.x < 0 ? 0.f : 1.f;
        const float m1 = nbc.y < 0 ? 0.f : 1.f;
        const float m2 = nbc.z < 0 ? 0.f : 1.f;
        const float m3 = nbc.w < 0 ? 0.f : 1.f;

        bf16x8 af[5];
#pragma unroll
        for (int h = 0; h < 2; ++h) {
#pragma unroll
            for (int j = 0; j < 4; ++j) {
                const int jj = h * 4 + j;
                const float va0 = cb[2 + h][j] * m0;
                const float va1 = cb[4 + h][j] * m1;
                const float vb0 = cb[6 + h][j] * m2;
                const float vb1 = cb[8 + h][j] * m3;
                const float sa = va0 + va1;
                const float da = fabsf(va0 - va1);
                const float sb = vb0 + vb1;
                const float db = fabsf(vb0 - vb1);
                af[0][jj] = (bf16_t)cb[h][j];
                af[1][jj] = (bf16_t)(sa + sb);
                af[2][jj] = (bf16_t)(da + db);
                af[3][jj] = (bf16_t)fabsf(sa - sb);
                af[4][jj] = (bf16_t)fabsf(da - db);
            }
        }

        f32x4 acc[4] = {{0.f,0.f,0.f,0.f},{0.f,0.f,0.f,0.f},
                        {0.f,0.f,0.f,0.f},{0.f,0.f,0.f,0.f}};
#pragma unroll
        for (int ks = 0; ks < 5; ++ks) {
#pragma unroll
            for (int tn = 0; tn < 4; ++tn) {
                const bf16x8 bfr = *(const bf16x8*)&w_lds[(((ks*4+tn)*4+quad)*16 + col) * 8];
                acc[tn] = __builtin_amdgcn_mfma_f32_16x16x32_bf16(af[ks], bfr, acc[tn], 0, 0, 0);
            }
        }

#pragma unroll
        for (int tn = 0; tn < 4; ++tn)
#pragma unroll
            for (int r = 0; r < 4; ++r)
                tw[(quad * 4 + r) * TSTR + tn * 16 + col] = acc[tn][r] + bv[tn];

#pragma unroll
        for (int r = 0; r < 4; ++r) {
            const f32x4 v = *(const f32x4*)&tw[(quad * 4 + r) * TSTR + col * 4];
            float* op = out + (size_t)(tile * MT + wave * 16 + quad * 4 + r) * OUTD + col * 4;
            __builtin_nontemporal_store(v, (f32x4*)op);
        }

        nbc = nbn;
#pragma unroll
        for (int k = 0; k < 10; ++k) cb[k] = pbuf[k];
    }
}

extern "C" void kernel_launch(void* const* d_in, const int* in_sizes, int n_in,
                              void* d_out, int out_size, void* d_ws, size_t ws_size,
                              hipStream_t stream) {
    const float* x    = (const float*)d_in[0];
    const int*   nbr  = (const int*)d_in[1];
    const float* W    = (const float*)d_in[2];
    const float* bias = (const float*)d_in[3];
    float* out = (float*)d_out;

    const size_t need = (size_t)EC * CCH * sizeof(f16_t);   // 64 MB fp16 image
    if (d_ws != nullptr && ws_size >= need) {
        f16_t* xh = (f16_t*)d_ws;
        cvt_x_f16<<<dim3(CVT_GRID), dim3(256), 0, stream>>>(x, xh);
        meshconv_f16<<<dim3(GRID_F16), dim3(256), 0, stream>>>(xh, nbr, W, bias, out);
    } else {
        meshconv_kernel<<<dim3(GRID_F32), dim3(256), 0, stream>>>(x, nbr, W, bias, out);
    }
}

// Round 4
// 493.219 us; speedup vs baseline: 1.3538x; 1.3538x over previous
//
#include <hip/hip_runtime.h>

// MeshConv R5: out[e][o] = b[o] + sum_k combined[e][k] * W[o][k], K=160, OUT=64.
//
// R4 post-mortem (correctness fail, absmax 6.06): the 4-phase epilogue's four
// LDS reads share ONE address (p-independent); cross-lane LDS dataflow is
// invisible to per-thread alias analysis, so GVN merged the later reads with
// the first -> stale data for ~3/4 of rows. Fix: asm volatile memory fences
// around each phase's read (compile-time only; HW DS ops are in-order per
// wave, so no extra waits needed).
//
// Carried from R3/R4 (perf theory, untested until now):
//  (1) R2's full-line LDS-transpose epilogue (WRITE == 250MB exactly), 4-row/
//      4-phase variant: t_lds 17KB -> 4.25KB.
//  (2) fp16-staged x (64MB image, L3-resident; fp16 rounding proven harmless
//      in R3: absmax unchanged at 0.03125). One 64B line per gathered row.
//  (3) occupancy: total LDS 24.8KB -> 6 blocks/CU = 24 waves (R2 had 16).
//      R3 measured 4.05 TB/s delivered at 62% occ vs R2's 3.5 at 22%.
//  (4) nbr indices prefetched 2 tiles ahead, gathers 1 tile ahead.
// Fallback: if ws_size < 64MB, run the proven R2 f32 kernel unchanged.

typedef __bf16    bf16_t;
typedef __bf16    bf16x8 __attribute__((ext_vector_type(8)));
typedef _Float16  f16_t;
typedef _Float16  f16x8  __attribute__((ext_vector_type(8)));
typedef float     f32x4  __attribute__((ext_vector_type(4)));

#define EC        1000000
#define CCH       32
#define OUTD      64
#define KD        160          // 5*CCH
#define MT        64           // elements per tile
#define NTILES    (EC / MT)    // 15625
#define NFRAG     1280         // 5 ks * 4 tn * 4 quad * 16 col frags of 8 bf16
#define TSTR      68           // epilogue LDS row stride (floats)
#define GRID_F16  1536         // 6 blocks/CU * 256 CUs
#define CVT_GRID  2048
#define GRID_F32  1024

// ---------------------------------------------------------------------------
// staging: x f32 -> f16 image in workspace. nt loads keep dead f32 out of the
// caches; cached stores prime L2/L3 with the fp16 image the gathers will hit.
// ---------------------------------------------------------------------------
__global__ __launch_bounds__(256)
void cvt_x_f16(const float* __restrict__ x, f16_t* __restrict__ xh)
{
    const size_t n8     = (size_t)EC * CCH / 8;     // 4,000,000 groups of 8
    const size_t stride = (size_t)CVT_GRID * 256;
    size_t i = (size_t)blockIdx.x * 256 + threadIdx.x;
    for (; i < n8; i += stride) {
        const f32x4* p = (const f32x4*)x + 2 * i;
        f32x4 a = __builtin_nontemporal_load(p);
        f32x4 b = __builtin_nontemporal_load(p + 1);
        f16x8 h;
        h[0]=(f16_t)a[0]; h[1]=(f16_t)a[1]; h[2]=(f16_t)a[2]; h[3]=(f16_t)a[3];
        h[4]=(f16_t)b[0]; h[5]=(f16_t)b[1]; h[6]=(f16_t)b[2]; h[7]=(f16_t)b[3];
        *((f16x8*)xh + i) = h;
    }
}

// ---------------------------------------------------------------------------
// main fp16-gather kernel (R2 MFMA orientation + fenced 4-phase epilogue)
// ---------------------------------------------------------------------------
__global__ __launch_bounds__(256, 6)
void meshconv_f16(const f16_t* __restrict__ xh,
                  const int*   __restrict__ nbr,
                  const float* __restrict__ W,
                  const float* __restrict__ bias,
                  float*       __restrict__ out)
{
    __shared__ bf16_t w_lds[NFRAG * 8];                              // 20.0 KB
    __shared__ __attribute__((aligned(16))) float t_lds[4 * 4 * TSTR]; // 4.25 KB

    const int tid  = threadIdx.x;
    const int wave = tid >> 6;
    const int lane = tid & 63;
    const int col  = lane & 15;
    const int quad = lane >> 4;

    // one-time: W (64x160 f32) -> bf16 LDS, frag-swizzled for the B operand:
    // frag(ks,tn,quad,col,j) = W[o = tn*16+col][k = ks*32 + quad*8 + j]
    for (int i = tid; i < NFRAG; i += 256) {
        const int fc  = i & 15;
        const int fq  = (i >> 4) & 3;
        const int ftn = (i >> 6) & 3;
        const int fks = i >> 8;
        const float* src = W + (ftn * 16 + fc) * KD + fks * 32 + fq * 8;
        f32x4 w0 = *(const f32x4*)src;
        f32x4 w1 = *(const f32x4*)(src + 4);
        bf16x8 wf;
        wf[0]=(bf16_t)w0[0]; wf[1]=(bf16_t)w0[1]; wf[2]=(bf16_t)w0[2]; wf[3]=(bf16_t)w0[3];
        wf[4]=(bf16_t)w1[0]; wf[5]=(bf16_t)w1[1]; wf[6]=(bf16_t)w1[2]; wf[7]=(bf16_t)w1[3];
        *(bf16x8*)&w_lds[i * 8] = wf;
    }

    float bv[4];
#pragma unroll
    for (int tn = 0; tn < 4; ++tn) bv[tn] = bias[tn * 16 + col];

    float* tw = &t_lds[wave * 4 * TSTR];   // per-wave 4-row region

    __syncthreads();   // w_lds ready; read-only hereafter

    auto ld_nbr = [&](int t) -> int4 {
        return ((const int4*)nbr)[t * MT + wave * 16 + col];
    };
    // 5 rows x 8 channels (this lane's quad slice): one 16B load per row;
    // 4 quads of a col coalesce to one 64B line per gathered row.
    auto gather = [&](int t, const int4& nb, f16x8* buf) {
        const int e  = t * MT + wave * 16 + col;
        const int i0 = nb.x < 0 ? 0 : nb.x;
        const int i1 = nb.y < 0 ? 0 : nb.y;
        const int i2 = nb.z < 0 ? 0 : nb.z;
        const int i3 = nb.w < 0 ? 0 : nb.w;
        const int co = quad * 8;
        buf[0] = *(const f16x8*)(xh + (size_t)e  * CCH + co);
        buf[1] = *(const f16x8*)(xh + (size_t)i0 * CCH + co);
        buf[2] = *(const f16x8*)(xh + (size_t)i1 * CCH + co);
        buf[3] = *(const f16x8*)(xh + (size_t)i2 * CCH + co);
        buf[4] = *(const f16x8*)(xh + (size_t)i3 * CCH + co);
    };

    int tile = blockIdx.x;
    int4  nb_cur, nb_nxt;
    f16x8 cb[5];
    if (tile < NTILES) {
        nb_cur = ld_nbr(tile);                  // prologue: serial once
        gather(tile, nb_cur, cb);
        const int t1 = (tile + GRID_F16 < NTILES) ? tile + GRID_F16 : tile;
        nb_nxt = ld_nbr(t1);
    }

    for (; tile < NTILES; tile += GRID_F16) {
        // ---- prefetch next tile (in flight through MFMA + epilogue) ----
        const int nxt = tile + GRID_F16;
        f16x8 pb[5];
        int4  nb2 = nb_nxt;
        if (nxt < NTILES) {
            gather(nxt, nb_nxt, pb);            // nbr already resident: no stall
            const int t2 = (nxt + GRID_F16 < NTILES) ? nxt + GRID_F16 : nxt;
            nb2 = ld_nbr(t2);                   // nbr two tiles ahead
        }

        // ---- descriptor slices == the 5 A-frags (M = col, k = quad*8+jj) ----
        const float m0 = nb_cur.x < 0 ? 0.f : 1.f;
        const float m1 = nb_cur.y < 0 ? 0.f : 1.f;
        const float m2 = nb_cur.z < 0 ? 0.f : 1.f;
        const float m3 = nb_cur.w < 0 ? 0.f : 1.f;

        bf16x8 af[5];
#pragma unroll
        for (int jj = 0; jj < 8; ++jj) {
            const float va0 = (float)cb[1][jj] * m0;
            const float va1 = (float)cb[2][jj] * m1;
            const float vb0 = (float)cb[3][jj] * m2;
            const float vb1 = (float)cb[4][jj] * m3;
            const float sa = va0 + va1;
            const float da = fabsf(va0 - va1);
            const float sb = vb0 + vb1;
            const float db = fabsf(vb0 - vb1);
            af[0][jj] = (bf16_t)(float)cb[0][jj];
            af[1][jj] = (bf16_t)(sa + sb);
            af[2][jj] = (bf16_t)(da + db);
            af[3][jj] = (bf16_t)fabsf(sa - sb);
            af[4][jj] = (bf16_t)fabsf(da - db);
        }

        // ---- MFMA: acc[tn][r] = C(e-row = quad*4+r, o = tn*16+col) ----
        f32x4 acc[4] = {{0.f,0.f,0.f,0.f},{0.f,0.f,0.f,0.f},
                        {0.f,0.f,0.f,0.f},{0.f,0.f,0.f,0.f}};
#pragma unroll
        for (int ks = 0; ks < 5; ++ks) {
#pragma unroll
            for (int tn = 0; tn < 4; ++tn) {
                const bf16x8 bfr = *(const bf16x8*)&w_lds[(((ks*4+tn)*4+quad)*16 + col) * 8];
                acc[tn] = __builtin_amdgcn_mfma_f32_16x16x32_bf16(af[ks], bfr, acc[tn], 0, 0, 0);
            }
        }

        // ---- epilogue: 4-phase in-wave LDS transpose -> full-line nt stores.
        // Phase p: quad-p lanes (holding e-rows p*4..p*4+3) write their 16
        // values; ALL lanes read back (local row `quad` -> e-row p*4+quad).
        // Cross-lane LDS dataflow is invisible to per-thread alias analysis
        // (R4's bug: the 4 identical-address reads were CSE'd) -> asm memory
        // fences make each phase's stores/load non-mergeable. HW-side, a
        // wave's DS ops execute in issue order, so no extra waits are needed.
        // Each nt store instruction covers 4 rows x 256B = 1KB contiguous.
#pragma unroll
        for (int p = 0; p < 4; ++p) {
            if (quad == p) {
#pragma unroll
                for (int tn = 0; tn < 4; ++tn)
#pragma unroll
                    for (int r = 0; r < 4; ++r)
                        tw[r * TSTR + tn * 16 + col] = acc[tn][r] + bv[tn];
            }
            asm volatile("" ::: "memory");   // stores above visible; no load CSE
            const f32x4 v = *(const f32x4*)&tw[quad * TSTR + col * 4];
            asm volatile("" ::: "memory");   // read done before next phase's writes
            float* op = out + (size_t)(tile * MT + wave * 16 + p * 4 + quad) * OUTD + col * 4;
            __builtin_nontemporal_store(v, (f32x4*)op);
        }

        // ---- rotate pipeline ----
        nb_cur = nb_nxt;
        nb_nxt = nb2;
#pragma unroll
        for (int k = 0; k < 5; ++k) cb[k] = pb[k];
    }
}

// ---------------------------------------------------------------------------
// R2 fallback (proven, 160us dispatch): f32 gathers + 16-row LDS transpose.
// Used only if the workspace cannot hold the 64MB fp16 image.
// ---------------------------------------------------------------------------
__global__ __launch_bounds__(256)
void meshconv_kernel(const float* __restrict__ x,
                     const int*   __restrict__ nbr,
                     const float* __restrict__ W,
                     const float* __restrict__ bias,
                     float*       __restrict__ out)
{
    __shared__ bf16_t w_lds[NFRAG * 8];
    __shared__ __attribute__((aligned(16))) float t_lds[4 * 16 * TSTR];

    const int tid  = threadIdx.x;
    const int wave = tid >> 6;
    const int lane = tid & 63;
    const int col  = lane & 15;
    const int quad = lane >> 4;

    for (int i = tid; i < NFRAG; i += 256) {
        const int fc  = i & 15;
        const int fq  = (i >> 4) & 3;
        const int ftn = (i >> 6) & 3;
        const int fks = i >> 8;
        const float* src = W + (ftn * 16 + fc) * KD + fks * 32 + fq * 8;
        f32x4 w0 = *(const f32x4*)src;
        f32x4 w1 = *(const f32x4*)(src + 4);
        bf16x8 wf;
        wf[0]=(bf16_t)w0[0]; wf[1]=(bf16_t)w0[1]; wf[2]=(bf16_t)w0[2]; wf[3]=(bf16_t)w0[3];
        wf[4]=(bf16_t)w1[0]; wf[5]=(bf16_t)w1[1]; wf[6]=(bf16_t)w1[2]; wf[7]=(bf16_t)w1[3];
        *(bf16x8*)&w_lds[i * 8] = wf;
    }

    float bv[4];
#pragma unroll
    for (int tn = 0; tn < 4; ++tn) bv[tn] = bias[tn * 16 + col];

    float* tw = &t_lds[wave * 16 * TSTR];

    __syncthreads();

    auto load_tile = [&](int t, int4& nb, f32x4* buf) {
        const int e = t * MT + wave * 16 + col;
        nb = ((const int4*)nbr)[e];
        const int i0 = nb.x < 0 ? 0 : nb.x;
        const int i1 = nb.y < 0 ? 0 : nb.y;
        const int i2 = nb.z < 0 ? 0 : nb.z;
        const int i3 = nb.w < 0 ? 0 : nb.w;
        const int co = quad * 8;
        const f32x4* p;
        p = (const f32x4*)(x + (size_t)e  * CCH + co); buf[0] = p[0]; buf[1] = p[1];
        p = (const f32x4*)(x + (size_t)i0 * CCH + co); buf[2] = p[0]; buf[3] = p[1];
        p = (const f32x4*)(x + (size_t)i1 * CCH + co); buf[4] = p[0]; buf[5] = p[1];
        p = (const f32x4*)(x + (size_t)i2 * CCH + co); buf[6] = p[0]; buf[7] = p[1];
        p = (const f32x4*)(x + (size_t)i3 * CCH + co); buf[8] = p[0]; buf[9] = p[1];
    };

    int tile = blockIdx.x;
    int4  nbc;
    f32x4 cb[10];
    if (tile < NTILES) load_tile(tile, nbc, cb);

    for (; tile < NTILES; tile += GRID_F32) {
        const int nxt = tile + GRID_F32;
        int4  nbn;
        f32x4 pbuf[10];
        if (nxt < NTILES) load_tile(nxt, nbn, pbuf);

        const float m0 = nbc.x < 0 ? 0.f : 1.f;
        const float m1 = nbc.y < 0 ? 0.f : 1.f;
        const float m2 = nbc.z < 0 ? 0.f : 1.f;
        const float m3 = nbc.w < 0 ? 0.f : 1.f;

        bf16x8 af[5];
#pragma unroll
        for (int h = 0; h < 2; ++h) {
#pragma unroll
            for (int j = 0; j < 4; ++j) {
                const int jj = h * 4 + j;
                const float va0 = cb[2 + h][j] * m0;
                const float va1 = cb[4 + h][j] * m1;
                const float vb0 = cb[6 + h][j] * m2;
                const float vb1 = cb[8 + h][j] * m3;
                const float sa = va0 + va1;
                const float da = fabsf(va0 - va1);
                const float sb = vb0 + vb1;
                const float db = fabsf(vb0 - vb1);
                af[0][jj] = (bf16_t)cb[h][j];
                af[1][jj] = (bf16_t)(sa + sb);
                af[2][jj] = (bf16_t)(da + db);
                af[3][jj] = (bf16_t)fabsf(sa - sb);
                af[4][jj] = (bf16_t)fabsf(da - db);
            }
        }

        f32x4 acc[4] = {{0.f,0.f,0.f,0.f},{0.f,0.f,0.f,0.f},
                        {0.f,0.f,0.f,0.f},{0.f,0.f,0.f,0.f}};
#pragma unroll
        for (int ks = 0; ks < 5; ++ks) {
#pragma unroll
            for (int tn = 0; tn < 4; ++tn) {
                const bf16x8 bfr = *(const bf16x8*)&w_lds[(((ks*4+tn)*4+quad)*16 + col) * 8];
                acc[tn] = __builtin_amdgcn_mfma_f32_16x16x32_bf16(af[ks], bfr, acc[tn], 0, 0, 0);
            }
        }

#pragma unroll
        for (int tn = 0; tn < 4; ++tn)
#pragma unroll
            for (int r = 0; r < 4; ++r)
                tw[(quad * 4 + r) * TSTR + tn * 16 + col] = acc[tn][r] + bv[tn];

        asm volatile("" ::: "memory");   // same hazard class as R4's bug: fence it

#pragma unroll
        for (int r = 0; r < 4; ++r) {
            const f32x4 v = *(const f32x4*)&tw[(quad * 4 + r) * TSTR + col * 4];
            float* op = out + (size_t)(tile * MT + wave * 16 + quad * 4 + r) * OUTD + col * 4;
            __builtin_nontemporal_store(v, (f32x4*)op);
        }

        asm volatile("" ::: "memory");

        nbc = nbn;
#pragma unroll
        for (int k = 0; k < 10; ++k) cb[k] = pbuf[k];
    }
}

extern "C" void kernel_launch(void* const* d_in, const int* in_sizes, int n_in,
                              void* d_out, int out_size, void* d_ws, size_t ws_size,
                              hipStream_t stream) {
    const float* x    = (const float*)d_in[0];
    const int*   nbr  = (const int*)d_in[1];
    const float* W    = (const float*)d_in[2];
    const float* bias = (const float*)d_in[3];
    float* out = (float*)d_out;

    const size_t need = (size_t)EC * CCH * sizeof(f16_t);   // 64 MB fp16 image
    if (d_ws != nullptr && ws_size >= need) {
        f16_t* xh = (f16_t*)d_ws;
        cvt_x_f16<<<dim3(CVT_GRID), dim3(256), 0, stream>>>(x, xh);
        meshconv_f16<<<dim3(GRID_F16), dim3(256), 0, stream>>>(xh, nbr, W, bias, out);
    } else {
        meshconv_kernel<<<dim3(GRID_F32), dim3(256), 0, stream>>>(x, nbr, W, bias, out);
    }
}